// Round 1
// baseline (282.636 us; speedup 1.0000x reference)
//
#include <hip/hip_runtime.h>
#include <hip/hip_bf16.h>

#define B_ 16
#define T_ 16384
#define C_ 8
#define L_ 16384
#define W_ 256
#define R_ 32

typedef __bf16 bf16x8 __attribute__((ext_vector_type(8)));
typedef float f32x4 __attribute__((ext_vector_type(4)));

// ---------------------------------------------------------------------------
// Kernel 1: x (B,T,C) fp32  ->  xt (B,C,L) bf16
// ---------------------------------------------------------------------------
__global__ void xconv_kernel(const float* __restrict__ x,
                             unsigned short* __restrict__ xt) {
  unsigned idx = blockIdx.x * 256u + threadIdx.x;   // [0, B*C*L) = 2^21
  unsigned t = idx & (L_ - 1);
  unsigned c = (idx >> 14) & (C_ - 1);
  unsigned b = idx >> 17;
  float v = x[((size_t)b * T_ + t) * C_ + c];
  __bf16 h = (__bf16)v;   // RTNE
  xt[idx] = __builtin_bit_cast(unsigned short, h);
}

// ---------------------------------------------------------------------------
// Kernel 2: Gabor bank -> Fg[c][j][w] bf16, j in [0,64): j<32 real(r=j),
// j>=32 imag(r=j-32); param index = c*32 + (31 - r)  (bakes the [::-1])
// ---------------------------------------------------------------------------
__global__ void gen_filters_kernel(const float* __restrict__ kv,
                                   const float* __restrict__ sv,
                                   unsigned short* __restrict__ Fg) {
  unsigned idx = blockIdx.x * 256u + threadIdx.x;   // [0, 8*64*256)
  unsigned w = idx & (W_ - 1);
  unsigned j = (idx >> 8) & 63u;
  unsigned c = idx >> 14;
  unsigned r = j & 31u;
  unsigned pidx = c * 32u + (31u - r);
  float k  = kv[pidx];
  float sg = sv[pidx];
  float phase = (-6.283185307179586f / (float)W_) * k * (float)w;
  float dn = (float)w - (float)(W_ / 2);
  float var2 = 2.0f * sg * sg;                       // 2*sigma^2
  float g = (1.0f / sqrtf(3.14159265358979f * var2)) * expf(-(dn * dn) / var2);
  float s, cth;
  sincosf(phase, &s, &cth);
  float v = (j < 32u) ? cth * g : s * g;
  __bf16 h = (__bf16)v;
  Fg[idx] = __builtin_bit_cast(unsigned short, h);
}

// ---------------------------------------------------------------------------
// Kernel 3: main MFMA kernel.
// Block = 256 threads = 4 waves, handles (b, c, 256 t-rows).
// Wave w handles rows [wv*64, wv*64+64) x all 64 filter columns.
// A[t][k] = xwin[t + k], xwin[i] = x[b,c, t0-128+i] (zero-padded).
// B[k][j] = F[j][k]  (filter rows contiguous -> consecutive-k reads).
// ---------------------------------------------------------------------------
__global__ __launch_bounds__(256, 2) void wavelet_main_kernel(
    const unsigned short* __restrict__ xt,   // [B][C][L] bf16
    const unsigned short* __restrict__ Fg,   // [C][64][256] bf16
    float* __restrict__ out)                 // [B][L][256] fp32
{
  // 64 filter rows, 256 bf16 each, padded to 264 bf16 (132 dwords) per row
  __shared__ __align__(16) unsigned int Fs[64 * 132];   // 33792 B
  __shared__ unsigned int xe[256];   // xe[d] = (xwin[2d],   xwin[2d+1])
  __shared__ unsigned int xo[256];   // xo[d] = (xwin[2d+1], xwin[2d+2])

  const int tid = threadIdx.x;
  const unsigned bid = blockIdx.x;
  const int tb = bid & 63;           // 64 t-blocks per (b,c)
  const int c  = (bid >> 6) & 7;
  const int b  = bid >> 9;
  const int t0 = tb << 8;            // 256 t per block

  // ---- stage filters: 64x256 bf16 = 2048 uint4 ----
  {
    const uint4* Fg4 = reinterpret_cast<const uint4*>(Fg + (size_t)c * (64 * 256));
    #pragma unroll
    for (int it = 0; it < 8; ++it) {
      int i = it * 256 + tid;
      uint4 v = Fg4[i];
      int j  = i >> 5;              // 32 uint4 per 256-bf16 row
      int wq = (i & 31) << 2;       // dword offset within row
      *reinterpret_cast<uint4*>(&Fs[j * 132 + wq]) = v;
    }
  }

  // ---- stage x window: xwin[i] = x[t0 - 128 + i], i in [0, 513) ----
  {
    const unsigned short* xrow = xt + ((size_t)b * C_ + c) * L_;
    int i0 = 2 * tid;
    int ta = t0 - 128 + i0;
    unsigned int v0 = (ta     >= 0 && ta     < L_) ? (unsigned int)xrow[ta]     : 0u;
    unsigned int v1 = (ta + 1 >= 0 && ta + 1 < L_) ? (unsigned int)xrow[ta + 1] : 0u;
    unsigned int v2 = (ta + 2 >= 0 && ta + 2 < L_) ? (unsigned int)xrow[ta + 2] : 0u;
    xe[tid] = v0 | (v1 << 16);
    xo[tid] = v1 | (v2 << 16);
  }
  __syncthreads();

  const int lane = tid & 63;
  const int wv   = tid >> 6;
  const int quad = lane >> 4;
  const int lrow = lane & 15;

  f32x4 acc[4][4];
  #pragma unroll
  for (int mt = 0; mt < 4; ++mt)
    #pragma unroll
    for (int nt = 0; nt < 4; ++nt)
      acc[mt][nt] = (f32x4){0.f, 0.f, 0.f, 0.f};

  #pragma unroll
  for (int kk = 0; kk < 8; ++kk) {
    const int k0 = kk * 32;

    // B fragments: lane reads F[nt*16+lrow][k0 + quad*8 .. +7] (16B aligned)
    bf16x8 bfr[4];
    #pragma unroll
    for (int nt = 0; nt < 4; ++nt) {
      const uint4 v = *reinterpret_cast<const uint4*>(
          &Fs[(nt * 16 + lrow) * 132 + (k0 >> 1) + quad * 4]);
      bfr[nt] = __builtin_bit_cast(bf16x8, v);
    }

    // A fragments: lane reads xwin[s .. s+7], s = row + k0 + quad*8
    bf16x8 afr[4];
    #pragma unroll
    for (int mt = 0; mt < 4; ++mt) {
      const int s = wv * 64 + mt * 16 + lrow + k0 + quad * 8;
      const unsigned int* src = (s & 1) ? xo : xe;
      const int d0 = s >> 1;
      uint4 v;
      v.x = src[d0]; v.y = src[d0 + 1]; v.z = src[d0 + 2]; v.w = src[d0 + 3];
      afr[mt] = __builtin_bit_cast(bf16x8, v);
    }

    #pragma unroll
    for (int mt = 0; mt < 4; ++mt)
      #pragma unroll
      for (int nt = 0; nt < 4; ++nt)
        acc[mt][nt] = __builtin_amdgcn_mfma_f32_16x16x32_bf16(
            afr[mt], bfr[nt], acc[mt][nt], 0, 0, 0);
  }

  // ---- epilogue: power = real^2 + imag^2 ----
  // D layout: row = quad*4 + i, col = lane&15 (per n-tile).
  // real cols: nt0 (0..15), nt1 (16..31); imag: nt2 (32..47), nt3 (48..63).
  const size_t obase = ((size_t)b * L_) * 256 + (size_t)c * 32 + lrow;
  #pragma unroll
  for (int mt = 0; mt < 4; ++mt) {
    #pragma unroll
    for (int i = 0; i < 4; ++i) {
      const int t = t0 + wv * 64 + mt * 16 + quad * 4 + i;
      float* orow = out + obase + (size_t)t * 256;
      orow[0]  = acc[mt][0][i] * acc[mt][0][i] + acc[mt][2][i] * acc[mt][2][i];
      orow[16] = acc[mt][1][i] * acc[mt][1][i] + acc[mt][3][i] * acc[mt][3][i];
    }
  }
}

// ---------------------------------------------------------------------------
extern "C" void kernel_launch(void* const* d_in, const int* in_sizes, int n_in,
                              void* d_out, int out_size, void* d_ws, size_t ws_size,
                              hipStream_t stream) {
  const float* x  = (const float*)d_in[0];
  const float* kv = (const float*)d_in[1];
  const float* sv = (const float*)d_in[2];
  float* out = (float*)d_out;

  unsigned short* xt = (unsigned short*)d_ws;                 // B*C*L bf16 = 4 MB
  unsigned short* Fg = xt + (size_t)B_ * C_ * L_;             // 8*64*256 bf16 = 256 KB

  hipLaunchKernelGGL(xconv_kernel, dim3((B_ * C_ * L_) / 256), dim3(256), 0, stream,
                     x, xt);
  hipLaunchKernelGGL(gen_filters_kernel, dim3((C_ * 64 * W_) / 256), dim3(256), 0, stream,
                     kv, sv, Fg);
  hipLaunchKernelGGL(wavelet_main_kernel, dim3(B_ * C_ * (L_ / 256)), dim3(256), 0, stream,
                     xt, Fg, out);
}